// Round 12
// baseline (150.305 us; speedup 1.0000x reference)
//
#include <hip/hip_runtime.h>

#define D      256
#define NROWS  8192
#define BHALF  4096
#define TILE   128
#define NT2    (NROWS / TILE)          // 64
#define NBLK   (NT2 * (NT2 + 1) / 2)   // 2080
#define NGRID  512                      // 2 blocks/CU (64 KB LDS) — co-resident
#define NBINS  64
#define QS     25.0f                   // int8 scale (5.08 sigma range)

typedef __attribute__((ext_vector_type(4))) int i32x4;

#if __has_builtin(__builtin_amdgcn_exp2f)
#define EXP2F(x) __builtin_amdgcn_exp2f(x)
#else
#define EXP2F(x) exp2f(x)
#endif

// ws layout (memset zeroes [0..2048)):
//   0     double sumsq
//   8     unsigned counter (finalize)
//   12    unsigned ready   (grid barrier)
//   16    double bins[64]           -> ends 528
//   1024  float colsum[256]         -> ends 2048
//   4096  float sq[8192]            -> ends 36864
//   36864 int8 Ti[8192][256] (2 MB) -> ends 2133888 (< proven ws_size)

__device__ __forceinline__ int q8(float x) {
    return (int)__builtin_rintf(fminf(fmaxf(x * QS, -127.f), 127.f));
}

__device__ __forceinline__ void gload_lds16(const signed char* g, signed char* l) {
    __builtin_amdgcn_global_load_lds(
        (const __attribute__((address_space(1))) unsigned int*)g,
        (__attribute__((address_space(3))) unsigned int*)l,
        16, 0, 0);
}

// ---------------------------------------------------------------- fused kernel
// Phase A: quantize 16 rows/block -> Ti, sq, colsum, sumsq.
// Grid spin-barrier (all 512 blocks co-resident: 64KB LDS -> exactly 2/CU).
// Phase C: R11 persistent tile loop, drain-free (all loads issued >=1 epilogue
// before their vmcnt wait).
__global__ __launch_bounds__(256, 2)
void mmd_fused(const float* __restrict__ src, const float* __restrict__ tar,
               signed char* __restrict__ Ti, float* __restrict__ sq,
               float* __restrict__ colsum, double* __restrict__ sumsq,
               double* __restrict__ bins, unsigned* __restrict__ counter,
               unsigned* __restrict__ ready, float* __restrict__ out)
{
    __shared__ signed char As[TILE * D];   // 32 KB: full-K A panel
    __shared__ signed char Bs[TILE * D];   // 32 KB: full-K B panel

    int t = threadIdx.x, lane = t & 63, wid = t >> 6;
    int wi = wid >> 1, wj = wid & 1;
    int lr = lane & 15, lk = lane >> 4;
    int bid = blockIdx.x;

    // ---------------- Phase A: pre (16 rows per block)
    {
        float* cs = (float*)As;            // reuse LDS before staging
        cs[t] = 0.f;
        __syncthreads();

        int rowBase = bid * 16 + wid * 4;
        float4 v[4];
        #pragma unroll
        for (int it = 0; it < 4; ++it) {
            int r = rowBase + it;
            const float* rowp = (r < BHALF) ? (src + (size_t)r * D)
                                            : (tar + (size_t)(r - BHALF) * D);
            v[it] = *(const float4*)(rowp + lane * 4);
        }
        float4 csum = make_float4(0.f, 0.f, 0.f, 0.f);
        float sqacc = 0.f;
        #pragma unroll
        for (int it = 0; it < 4; ++it) {
            int r = rowBase + it;
            int q0 = q8(v[it].x), q1 = q8(v[it].y), q2 = q8(v[it].z), q3 = q8(v[it].w);
            unsigned pk = (unsigned)(q0 & 255) | ((unsigned)(q1 & 255) << 8) |
                          ((unsigned)(q2 & 255) << 16) | ((unsigned)(q3 & 255) << 24);
            *(unsigned*)(Ti + (size_t)r * D + lane * 4) = pk;
            csum.x += v[it].x; csum.y += v[it].y; csum.z += v[it].z; csum.w += v[it].w;
            float s = v[it].x * v[it].x + v[it].y * v[it].y +
                      v[it].z * v[it].z + v[it].w * v[it].w;
            #pragma unroll
            for (int off = 32; off; off >>= 1) s += __shfl_xor(s, off, 64);
            if (lane == 0) { sq[r] = s; sqacc += s; }
        }
        atomicAdd(&cs[lane * 4 + 0], csum.x);
        atomicAdd(&cs[lane * 4 + 1], csum.y);
        atomicAdd(&cs[lane * 4 + 2], csum.z);
        atomicAdd(&cs[lane * 4 + 3], csum.w);
        if (lane == 0) atomicAdd(sumsq, (double)sqacc);
        __syncthreads();
        atomicAdd(&colsum[t], cs[t]);
        __syncthreads();                   // all this block's work issued+drained

        // ---------------- grid spin-barrier (co-resident by construction)
        if (t == 0) {
            __threadfence();               // release: Ti/sq/colsum visible
            atomicAdd(ready, 1u);
            while (__hip_atomic_load(ready, __ATOMIC_ACQUIRE,
                                     __HIP_MEMORY_SCOPE_AGENT) < NGRID)
                __builtin_amdgcn_s_sleep(2);
            __threadfence();               // acquire
        }
        __syncthreads();
    }

    // ---------------- Phase B: bandwidth -> g2 (redundant per thread)
    float4 c4 = *(const float4*)(colsum + lane * 4);
    float s = c4.x * c4.x + c4.y * c4.y + c4.z * c4.z + c4.w * c4.w;
    #pragma unroll
    for (int off = 32; off; off >>= 1) s += __shfl_xor(s, off, 64);
    double sumL2 = 2.0 * (double)NROWS * (*sumsq) - 2.0 * (double)s;
    double bwd = sumL2 / ((double)NROWS * (double)NROWS - (double)NROWS) / 4.0;
    float g2 = (float)(1.4426950408889634 / (16.0 * bwd));
    float c2 = 2.f * g2 / (QS * QS);       // e = c2*idot - (gsi+gsj)

    // ---------------- Phase C: persistent tile loop
    int sw = (bid & 7) * (NGRID / 8) + (bid >> 3);
    int pstart = (int)(((long)sw * NBLK) / NGRID);
    int pend   = (int)(((long)(sw + 1) * NBLK) / NGRID);

    int ti, tj;
    {
        int rem = pstart, a = 0;
        while (rem >= NT2 - a) { rem -= NT2 - a; ++a; }
        ti = a; tj = a + rem;
    }

    auto stage = [&](signed char* dst, int tt) {
        const signed char* g = Ti + (size_t)tt * TILE * D;
        #pragma unroll
        for (int p = 0; p < 8; ++p) {
            int q = p * 256 + t;            // 16B-chunk id, 0..2047
            int row = q >> 4, c = q & 15;
            gload_lds16(g + row * D + ((c ^ (row & 7)) << 4), dst + (q << 4));
        }
    };

    stage(As, ti);
    stage(Bs, tj);

    float gsi[4][4], gsj[4];
    int gsiA = -1;
    float running = 0.f;

    for (int p = pstart; p < pend; ++p) {
        // drain: everything outstanding was issued >= one epilogue ago
        asm volatile("s_waitcnt vmcnt(0)" ::: "memory");
        __syncthreads();                   // panels ready

        i32x4 acc[4][4];
        #pragma unroll
        for (int m = 0; m < 4; ++m)
            #pragma unroll
            for (int n = 0; n < 4; ++n)
                acc[m][n] = (i32x4){0, 0, 0, 0};

        // full-K MFMA sweep from LDS, no barriers inside
        #pragma unroll
        for (int ks = 0; ks < 4; ++ks) {
            i32x4 av[4], bv[4];
            int ca = ks * 4 + lk;          // 16B-chunk index, 0..15
            #pragma unroll
            for (int m = 0; m < 4; ++m) {
                int rA = wi * 64 + m * 16 + lr;
                av[m] = *(const i32x4*)&As[rA * D + ((ca ^ (rA & 7)) << 4)];
            }
            #pragma unroll
            for (int n = 0; n < 4; ++n) {
                int rB = wj * 64 + n * 16 + lr;
                bv[n] = *(const i32x4*)&Bs[rB * D + ((ca ^ (rB & 7)) << 4)];
            }
            #pragma unroll
            for (int m = 0; m < 4; ++m)
                #pragma unroll
                for (int n = 0; n < 4; ++n)
                    acc[m][n] = __builtin_amdgcn_mfma_i32_16x16x64_i8(
                                    av[m], bv[n], acc[m][n], 0, 0, 0);
        }
        __syncthreads();                   // all panel reads done

        // issue next pair's staging; latency hides under the epilogue
        int nti = ti, ntj = tj + 1;
        if (ntj >= NT2) { nti = ti + 1; ntj = nti; }
        if (p + 1 < pend) {
            stage(Bs, ntj);
            if (nti != ti) stage(As, nti);
        }

        // sq operands for the CURRENT pair — out of the drain path
        int rowA = ti * TILE + wi * 64, rowB = tj * TILE + wj * 64;
        if (ti != gsiA) {
            #pragma unroll
            for (int m = 0; m < 4; ++m)
                #pragma unroll
                for (int r = 0; r < 4; ++r)
                    gsi[m][r] = g2 * sq[rowA + m * 16 + lk * 4 + r];
            gsiA = ti;
        }
        #pragma unroll
        for (int n = 0; n < 4; ++n) gsj[n] = g2 * sq[rowB + n * 16 + lr];

        // epilogue: e = min(c2*idot - (gsi+gsj), 0); u = 2^e; 5 powers
        bool strad = (ti == tj);
        float lanesum = 0.f;
        #pragma unroll
        for (int m = 0; m < 4; ++m) {
            #pragma unroll
            for (int r = 0; r < 4; ++r) {
                float gi_s = gsi[m][r];
                #pragma unroll
                for (int n = 0; n < 4; ++n) {
                    float fd = (float)acc[m][n][r];
                    float e  = fminf(fmaf(c2, fd, -(gi_s + gsj[n])), 0.f);
                    float uu = EXP2F(e);
                    float u2 = uu * uu, u4 = u2 * u2, u8 = u4 * u4, u16 = u8 * u8;
                    float s5 = uu + u2 + u4 + u8 + u16;
                    if (strad) {
                        int gi = rowA + m * 16 + lk * 4 + r;
                        int gj = rowB + n * 16 + lr;
                        float w = (gj > gi) ? 2.f : ((gj == gi) ? 1.f : 0.f);
                        lanesum = fmaf(w, s5, lanesum);
                    } else {
                        lanesum += s5;
                    }
                }
            }
        }
        float sgn = ((ti < NT2 / 2) == (tj < NT2 / 2)) ? 1.f : -1.f;
        running = fmaf(strad ? sgn : 2.f * sgn, lanesum, running);

        ti = nti; tj = ntj;
    }

    // one reduce + one atomic per wave
    #pragma unroll
    for (int off = 32; off; off >>= 1) running += __shfl_xor(running, off, 64);
    if (lane == 0)
        atomicAdd(&bins[((sw << 2) + wid) & (NBINS - 1)], (double)running);

    __syncthreads();
    if (t == 0) {
        __threadfence();
        unsigned old = atomicAdd(counter, 1u);
        if (old == NGRID - 1) {            // last block finalizes
            __threadfence();
            double tot = 0.0;
            for (int i = 0; i < NBINS; ++i)
                tot += ((volatile double*)bins)[i];
            out[0] = (float)(tot / ((double)BHALF * (double)BHALF));
        }
    }
}

extern "C" void kernel_launch(void* const* d_in, const int* in_sizes, int n_in,
                              void* d_out, int out_size, void* d_ws, size_t ws_size,
                              hipStream_t stream) {
    const float* src = (const float*)d_in[0];
    const float* tar = (const float*)d_in[1];
    float* out = (float*)d_out;

    char* ws = (char*)d_ws;
    double*   sumsq   = (double*)(ws + 0);
    unsigned* counter = (unsigned*)(ws + 8);
    unsigned* ready   = (unsigned*)(ws + 12);
    double*   bins    = (double*)(ws + 16);
    float*    colsum  = (float*)(ws + 1024);
    float*    sq      = (float*)(ws + 4096);
    signed char* Ti   = (signed char*)(ws + 36864);

    hipMemsetAsync(ws, 0, 2048, stream);
    mmd_fused<<<NGRID, 256, 0, stream>>>(src, tar, Ti, sq, colsum, sumsq,
                                         bins, counter, ready, out);
}

// Round 13
// 129.411 us; speedup vs baseline: 1.1615x; 1.1615x over previous
//
#include <hip/hip_runtime.h>

#define D      256
#define NROWS  8192
#define BHALF  4096
#define TILE   64
#define NT2    (NROWS / TILE)          // 128
#define NBLK   (NT2 * (NT2 + 1) / 2)   // 8256
#define NGRID  1280                     // 5 blocks/CU (32 KB LDS each)
#define NBINS  64
#define QS     25.0f                   // int8 scale (5.08 sigma range)

typedef __attribute__((ext_vector_type(4))) int i32x4;

#if __has_builtin(__builtin_amdgcn_exp2f)
#define EXP2F(x) __builtin_amdgcn_exp2f(x)
#else
#define EXP2F(x) exp2f(x)
#endif

// ws layout (memset zeroes [0..2048)):
//   0     double sumsq
//   8     unsigned counter
//   16    double bins[64]           -> ends 528
//   1024  float colsum[256]         -> ends 2048
//   4096  float sq[8192]            -> ends 36864
//   36864 int8 Ti[8192][256] (2 MB) -> ends 2133888 (< proven ws_size)

__device__ __forceinline__ int q8(float x) {
    return (int)__builtin_rintf(fminf(fmaxf(x * QS, -127.f), 127.f));
}

__device__ __forceinline__ void gload_lds16(const signed char* g, signed char* l) {
    __builtin_amdgcn_global_load_lds(
        (const __attribute__((address_space(1))) unsigned int*)g,
        (__attribute__((address_space(3))) unsigned int*)l,
        16, 0, 0);
}

// ---------------------------------------------------------------- pass 1 (R11, proven)
__global__ __launch_bounds__(256)
void pre_kernel(const float* __restrict__ src, const float* __restrict__ tar,
                float* __restrict__ sq, float* __restrict__ colsum,
                double* __restrict__ sumsq, signed char* __restrict__ Ti) {
    __shared__ float cs[D];
    int t = threadIdx.x;
    cs[t] = 0.f;
    __syncthreads();

    int lane = t & 63, w = t >> 6;
    int rowBase = blockIdx.x * 32 + w * 8;

    float4 v[8];
    #pragma unroll
    for (int it = 0; it < 8; ++it) {
        int r = rowBase + it;
        const float* rowp = (r < BHALF) ? (src + (size_t)r * D)
                                        : (tar + (size_t)(r - BHALF) * D);
        v[it] = *(const float4*)(rowp + lane * 4);
    }

    float4 csum = make_float4(0.f, 0.f, 0.f, 0.f);
    float sqacc = 0.f;
    #pragma unroll
    for (int it = 0; it < 8; ++it) {
        int r = rowBase + it;
        int q0 = q8(v[it].x), q1 = q8(v[it].y), q2 = q8(v[it].z), q3 = q8(v[it].w);
        unsigned pk = (unsigned)(q0 & 255) | ((unsigned)(q1 & 255) << 8) |
                      ((unsigned)(q2 & 255) << 16) | ((unsigned)(q3 & 255) << 24);
        *(unsigned*)(Ti + (size_t)r * D + lane * 4) = pk;
        csum.x += v[it].x; csum.y += v[it].y; csum.z += v[it].z; csum.w += v[it].w;
        float s = v[it].x * v[it].x + v[it].y * v[it].y +
                  v[it].z * v[it].z + v[it].w * v[it].w;
        #pragma unroll
        for (int off = 32; off; off >>= 1) s += __shfl_xor(s, off, 64);
        if (lane == 0) { sq[r] = s; sqacc += s; }
    }
    atomicAdd(&cs[lane * 4 + 0], csum.x);
    atomicAdd(&cs[lane * 4 + 1], csum.y);
    atomicAdd(&cs[lane * 4 + 2], csum.z);
    atomicAdd(&cs[lane * 4 + 3], csum.w);
    if (lane == 0) atomicAdd(sumsq, (double)sqacc);
    __syncthreads();
    atomicAdd(&colsum[t], cs[t]);
}

// ---------------------------------------------------------------- main (persistent)
// R11 structure at TILE=64: 32 KB LDS -> 5 blocks/CU -> 5 waves/SIMD.
// Cross-block TLP hides the per-pair drain convoy.
__global__ __launch_bounds__(256, 5)
void mmd_main(const signed char* __restrict__ Ti,
              const float* __restrict__ sq, const float* __restrict__ colsum,
              const double* __restrict__ sumsq,
              double* __restrict__ bins, unsigned* __restrict__ counter,
              float* __restrict__ out)
{
    __shared__ signed char As[TILE * D];   // 16 KB: full-K A panel
    __shared__ signed char Bs[TILE * D];   // 16 KB: full-K B panel

    int t = threadIdx.x, lane = t & 63, wid = t >> 6;
    int wi = wid >> 1, wj = wid & 1;       // 2x2 waves over 64x64 tile
    int lr = lane & 15, lk = lane >> 4;

    // XCD-contiguous pair runs (1280 % 8 == 0, bijective)
    int bid = blockIdx.x;
    int sw = (bid & 7) * (NGRID / 8) + (bid >> 3);
    int pstart = (int)(((long)sw * NBLK) / NGRID);
    int pend   = (int)(((long)(sw + 1) * NBLK) / NGRID);

    int ti, tj;
    {
        int rem = pstart, a = 0;
        while (rem >= NT2 - a) { rem -= NT2 - a; ++a; }
        ti = a; tj = a + rem;
    }

    // staging: LDS linear [row][chunk], source chunk pre-swizzled c^(row&7)
    // (16B chunks, 16 per 256B row) — involution pair with the reads
    auto stage = [&](signed char* dst, int tt) {
        const signed char* g = Ti + (size_t)tt * TILE * D;
        #pragma unroll
        for (int p = 0; p < 4; ++p) {
            int q = p * 256 + t;            // 16B-chunk id, 0..1023
            int row = q >> 4, c = q & 15;
            gload_lds16(g + row * D + ((c ^ (row & 7)) << 4), dst + (q << 4));
        }
    };

    stage(As, ti);
    stage(Bs, tj);

    // bandwidth -> g2, per block (overlaps first stage)
    float4 c4 = *(const float4*)(colsum + lane * 4);
    float s = c4.x * c4.x + c4.y * c4.y + c4.z * c4.z + c4.w * c4.w;
    #pragma unroll
    for (int off = 32; off; off >>= 1) s += __shfl_xor(s, off, 64);
    double sumL2 = 2.0 * (double)NROWS * (*sumsq) - 2.0 * (double)s;
    double bwd = sumL2 / ((double)NROWS * (double)NROWS - (double)NROWS) / 4.0;
    float g2 = (float)(1.4426950408889634 / (16.0 * bwd));
    float c2 = 2.f * g2 / (QS * QS);       // e = c2*idot - (gsi+gsj)

    float running = 0.f;

    for (int p = pstart; p < pend; ++p) {
        // epilogue operands: independent loads issued before the drain
        int rowA = ti * TILE + wi * 32, rowB = tj * TILE + wj * 32;
        float gsj[2], gsi[2][4];
        #pragma unroll
        for (int n = 0; n < 2; ++n) gsj[n] = g2 * sq[rowB + n * 16 + lr];
        #pragma unroll
        for (int m = 0; m < 2; ++m)
            #pragma unroll
            for (int r = 0; r < 4; ++r)
                gsi[m][r] = g2 * sq[rowA + m * 16 + lk * 4 + r];

        asm volatile("s_waitcnt vmcnt(0)" ::: "memory");
        __syncthreads();                   // panels ready

        i32x4 acc[2][2];
        #pragma unroll
        for (int m = 0; m < 2; ++m)
            #pragma unroll
            for (int n = 0; n < 2; ++n)
                acc[m][n] = (i32x4){0, 0, 0, 0};

        // full-K MFMA sweep from LDS, no barriers inside
        #pragma unroll
        for (int ks = 0; ks < 4; ++ks) {
            i32x4 av[2], bv[2];
            int ca = ks * 4 + lk;          // 16B-chunk index, 0..15
            #pragma unroll
            for (int m = 0; m < 2; ++m) {
                int rA = wi * 32 + m * 16 + lr;
                av[m] = *(const i32x4*)&As[rA * D + ((ca ^ (rA & 7)) << 4)];
            }
            #pragma unroll
            for (int n = 0; n < 2; ++n) {
                int rB = wj * 32 + n * 16 + lr;
                bv[n] = *(const i32x4*)&Bs[rB * D + ((ca ^ (rB & 7)) << 4)];
            }
            #pragma unroll
            for (int m = 0; m < 2; ++m)
                #pragma unroll
                for (int n = 0; n < 2; ++n)
                    acc[m][n] = __builtin_amdgcn_mfma_i32_16x16x64_i8(
                                    av[m], bv[n], acc[m][n], 0, 0, 0);
        }
        __syncthreads();                   // all panel reads done

        // issue next pair's staging; latency hides under the epilogue
        int nti = ti, ntj = tj + 1;
        if (ntj >= NT2) { nti = ti + 1; ntj = nti; }
        if (p + 1 < pend) {
            stage(Bs, ntj);
            if (nti != ti) stage(As, nti);
        }

        // epilogue: e = min(c2*idot - (gsi+gsj), 0); u = 2^e; 5 powers
        bool strad = (ti == tj);
        float lanesum = 0.f;
        #pragma unroll
        for (int m = 0; m < 2; ++m) {
            #pragma unroll
            for (int r = 0; r < 4; ++r) {
                float gi_s = gsi[m][r];
                #pragma unroll
                for (int n = 0; n < 2; ++n) {
                    float fd = (float)acc[m][n][r];
                    float e  = fminf(fmaf(c2, fd, -(gi_s + gsj[n])), 0.f);
                    float uu = EXP2F(e);
                    float u2 = uu * uu, u4 = u2 * u2, u8 = u4 * u4, u16 = u8 * u8;
                    float s5 = uu + u2 + u4 + u8 + u16;
                    if (strad) {
                        int gi = rowA + m * 16 + lk * 4 + r;
                        int gj = rowB + n * 16 + lr;
                        float w = (gj > gi) ? 2.f : ((gj == gi) ? 1.f : 0.f);
                        lanesum = fmaf(w, s5, lanesum);
                    } else {
                        lanesum += s5;
                    }
                }
            }
        }
        float sgn = ((ti < NT2 / 2) == (tj < NT2 / 2)) ? 1.f : -1.f;
        running = fmaf(strad ? sgn : 2.f * sgn, lanesum, running);

        ti = nti; tj = ntj;
    }

    // one reduce + one atomic per wave
    #pragma unroll
    for (int off = 32; off; off >>= 1) running += __shfl_xor(running, off, 64);
    if (lane == 0)
        atomicAdd(&bins[((sw << 2) + wid) & (NBINS - 1)], (double)running);

    __syncthreads();
    if (t == 0) {
        __threadfence();
        unsigned old = atomicAdd(counter, 1u);
        if (old == NGRID - 1) {            // last block finalizes
            __threadfence();
            double tot = 0.0;
            for (int i = 0; i < NBINS; ++i)
                tot += ((volatile double*)bins)[i];
            out[0] = (float)(tot / ((double)BHALF * (double)BHALF));
        }
    }
}

extern "C" void kernel_launch(void* const* d_in, const int* in_sizes, int n_in,
                              void* d_out, int out_size, void* d_ws, size_t ws_size,
                              hipStream_t stream) {
    const float* src = (const float*)d_in[0];
    const float* tar = (const float*)d_in[1];
    float* out = (float*)d_out;

    char* ws = (char*)d_ws;
    double*   sumsq   = (double*)(ws + 0);
    unsigned* counter = (unsigned*)(ws + 8);
    double*   bins    = (double*)(ws + 16);
    float*    colsum  = (float*)(ws + 1024);
    float*    sq      = (float*)(ws + 4096);
    signed char* Ti   = (signed char*)(ws + 36864);

    hipMemsetAsync(ws, 0, 2048, stream);
    pre_kernel<<<256, 256, 0, stream>>>(src, tar, sq, colsum, sumsq, Ti);
    mmd_main<<<NGRID, 256, 0, stream>>>(Ti, sq, colsum, sumsq, bins, counter, out);
}

// Round 14
// 114.860 us; speedup vs baseline: 1.3086x; 1.1267x over previous
//
#include <hip/hip_runtime.h>

#define D      256
#define NROWS  8192
#define BHALF  4096
#define TA     128                     // A tile rows (32 KB int8, full K)
#define TB     64                      // B band rows (16 KB int8) x2 buffers
#define NTA    (NROWS / TA)            // 64
#define NTB    (NROWS / TB)            // 128
#define NPAIR  4160                    // sum_{ti<64} (128 - 2*ti)
#define NGRID  512                     // 2 blocks/CU (64 KB LDS each)
#define NBINS  64
#define QS     25.0f                   // int8 scale (5.08 sigma range)

typedef __attribute__((ext_vector_type(4))) int i32x4;

#if __has_builtin(__builtin_amdgcn_exp2f)
#define EXP2F(x) __builtin_amdgcn_exp2f(x)
#else
#define EXP2F(x) exp2f(x)
#endif

// ws layout (memset zeroes [0..2048)):
//   0     double sumsq
//   8     unsigned counter
//   16    double bins[64]           -> ends 528
//   1024  float colsum[256]         -> ends 2048
//   4096  float sq[8192]            -> ends 36864
//   36864 int8 Ti[8192][256] (2 MB) -> ends 2133888 (< proven ws_size)

__device__ __forceinline__ int q8(float x) {
    return (int)__builtin_rintf(fminf(fmaxf(x * QS, -127.f), 127.f));
}

__device__ __forceinline__ void gload_lds16(const signed char* g, signed char* l) {
    __builtin_amdgcn_global_load_lds(
        (const __attribute__((address_space(1))) unsigned int*)g,
        (__attribute__((address_space(3))) unsigned int*)l,
        16, 0, 0);
}

// ---------------------------------------------------------------- pass 1 (proven)
__global__ __launch_bounds__(256)
void pre_kernel(const float* __restrict__ src, const float* __restrict__ tar,
                float* __restrict__ sq, float* __restrict__ colsum,
                double* __restrict__ sumsq, signed char* __restrict__ Ti) {
    __shared__ float cs[D];
    int t = threadIdx.x;
    cs[t] = 0.f;
    __syncthreads();

    int lane = t & 63, w = t >> 6;
    int rowBase = blockIdx.x * 32 + w * 8;

    float4 v[8];
    #pragma unroll
    for (int it = 0; it < 8; ++it) {
        int r = rowBase + it;
        const float* rowp = (r < BHALF) ? (src + (size_t)r * D)
                                        : (tar + (size_t)(r - BHALF) * D);
        v[it] = *(const float4*)(rowp + lane * 4);
    }

    float4 csum = make_float4(0.f, 0.f, 0.f, 0.f);
    float sqacc = 0.f;
    #pragma unroll
    for (int it = 0; it < 8; ++it) {
        int r = rowBase + it;
        int q0 = q8(v[it].x), q1 = q8(v[it].y), q2 = q8(v[it].z), q3 = q8(v[it].w);
        unsigned pk = (unsigned)(q0 & 255) | ((unsigned)(q1 & 255) << 8) |
                      ((unsigned)(q2 & 255) << 16) | ((unsigned)(q3 & 255) << 24);
        *(unsigned*)(Ti + (size_t)r * D + lane * 4) = pk;
        csum.x += v[it].x; csum.y += v[it].y; csum.z += v[it].z; csum.w += v[it].w;
        float s = v[it].x * v[it].x + v[it].y * v[it].y +
                  v[it].z * v[it].z + v[it].w * v[it].w;
        #pragma unroll
        for (int off = 32; off; off >>= 1) s += __shfl_xor(s, off, 64);
        if (lane == 0) { sq[r] = s; sqacc += s; }
    }
    atomicAdd(&cs[lane * 4 + 0], csum.x);
    atomicAdd(&cs[lane * 4 + 1], csum.y);
    atomicAdd(&cs[lane * 4 + 2], csum.z);
    atomicAdd(&cs[lane * 4 + 3], csum.w);
    if (lane == 0) atomicAdd(sumsq, (double)sqacc);
    __syncthreads();
    atomicAdd(&colsum[t], cs[t]);
}

// ---------------------------------------------------------------- main (persistent)
// A panel (128 rows) staged ~once per run; B panels double-buffered so the
// vmcnt(0) drain only waits on loads issued a full pair earlier (complete).
__global__ __launch_bounds__(256, 2)
void mmd_main(const signed char* __restrict__ Ti,
              const float* __restrict__ sq, const float* __restrict__ colsum,
              const double* __restrict__ sumsq,
              double* __restrict__ bins, unsigned* __restrict__ counter,
              float* __restrict__ out)
{
    __shared__ signed char As[TA * D];        // 32 KB
    __shared__ signed char Bs[2][TB * D];     // 2 x 16 KB

    int t = threadIdx.x, lane = t & 63, wid = t >> 6;   // wave owns 32 A rows
    int lr = lane & 15, lk = lane >> 4;

    // XCD-contiguous pair runs (512 % 8 == 0, bijective)
    int bid = blockIdx.x;
    int sw = (bid & 7) * (NGRID / 8) + (bid >> 3);
    int pstart = (int)(((long)sw * NPAIR) / NGRID);
    int pend   = (int)(((long)(sw + 1) * NPAIR) / NGRID);

    // pair p -> (ti, tj): ti in 0..63, tj in 2*ti..127
    int ti, tj;
    {
        int rem = pstart, a = 0;
        while (rem >= NTB - 2 * a) { rem -= NTB - 2 * a; ++a; }
        ti = a; tj = 2 * a + rem;
    }

    auto stageA = [&](int tt) {
        const signed char* g = Ti + (size_t)tt * TA * D;
        #pragma unroll
        for (int p = 0; p < 8; ++p) {
            int q = p * 256 + t;             // 16B-chunk id, 0..2047
            int row = q >> 4, c = q & 15;
            gload_lds16(g + row * D + ((c ^ (row & 7)) << 4), As + (q << 4));
        }
    };
    auto stageB = [&](int buf, int tt) {
        const signed char* g = Ti + (size_t)tt * TB * D;
        #pragma unroll
        for (int p = 0; p < 4; ++p) {
            int q = p * 256 + t;             // 16B-chunk id, 0..1023
            int row = q >> 4, c = q & 15;
            gload_lds16(g + row * D + ((c ^ (row & 7)) << 4), Bs[buf] + (q << 4));
        }
    };

    stageA(ti);
    stageB(0, tj);

    // bandwidth -> g2, per block (overlaps first stage)
    float4 c4 = *(const float4*)(colsum + lane * 4);
    float s = c4.x * c4.x + c4.y * c4.y + c4.z * c4.z + c4.w * c4.w;
    #pragma unroll
    for (int off = 32; off; off >>= 1) s += __shfl_xor(s, off, 64);
    double sumL2 = 2.0 * (double)NROWS * (*sumsq) - 2.0 * (double)s;
    double bwd = sumL2 / ((double)NROWS * (double)NROWS - (double)NROWS) / 4.0;
    float g2 = (float)(1.4426950408889634 / (16.0 * bwd));
    float c2 = 2.f * g2 / (QS * QS);         // e = c2*idot - (gsi+gsj)

    // epilogue operands for the FIRST pair (one-time, drained with prologue)
    float gsi[2][4], gsj[4];
    #pragma unroll
    for (int m = 0; m < 2; ++m)
        #pragma unroll
        for (int r = 0; r < 4; ++r)
            gsi[m][r] = g2 * sq[ti * TA + wid * 32 + m * 16 + lk * 4 + r];
    #pragma unroll
    for (int n = 0; n < 4; ++n) gsj[n] = g2 * sq[tj * TB + n * 16 + lr];

    float running = 0.f;
    int cur = 0;

    for (int p = pstart; p < pend; ++p) {
        // drain: B[cur] (and A if restaged) were issued >= one full pair ago
        asm volatile("s_waitcnt vmcnt(0)" ::: "memory");
        __syncthreads();

        i32x4 acc[2][4];
        #pragma unroll
        for (int m = 0; m < 2; ++m)
            #pragma unroll
            for (int n = 0; n < 4; ++n)
                acc[m][n] = (i32x4){0, 0, 0, 0};

        // full-K MFMA sweep: A rows wid*32..+32, all 64 B rows
        #pragma unroll
        for (int ks = 0; ks < 4; ++ks) {
            i32x4 av[2], bv[4];
            int ca = ks * 4 + lk;            // 16B-chunk index, 0..15
            #pragma unroll
            for (int m = 0; m < 2; ++m) {
                int rA = wid * 32 + m * 16 + lr;
                av[m] = *(const i32x4*)&As[rA * D + ((ca ^ (rA & 7)) << 4)];
            }
            #pragma unroll
            for (int n = 0; n < 4; ++n) {
                int rB = n * 16 + lr;
                bv[n] = *(const i32x4*)&Bs[cur][rB * D + ((ca ^ (rB & 7)) << 4)];
            }
            #pragma unroll
            for (int m = 0; m < 2; ++m)
                #pragma unroll
                for (int n = 0; n < 4; ++n)
                    acc[m][n] = __builtin_amdgcn_mfma_i32_16x16x64_i8(
                                    av[m], bv[n], acc[m][n], 0, 0, 0);
        }
        __syncthreads();                     // all reads of As/Bs[cur] done

        // advance + issue next pair's staging and sq loads (hide under epilogue)
        int nti = ti, ntj = tj + 1;
        if (ntj >= NTB) { ++nti; ntj = 2 * nti; }
        float ngsi[2][4], ngsj[4];
        if (p + 1 < pend) {
            stageB(cur ^ 1, ntj);
            if (nti != ti) stageA(nti);
            if (nti != ti) {
                #pragma unroll
                for (int m = 0; m < 2; ++m)
                    #pragma unroll
                    for (int r = 0; r < 4; ++r)
                        ngsi[m][r] = g2 * sq[nti * TA + wid * 32 + m * 16 + lk * 4 + r];
            } else {
                #pragma unroll
                for (int m = 0; m < 2; ++m)
                    #pragma unroll
                    for (int r = 0; r < 4; ++r)
                        ngsi[m][r] = gsi[m][r];
            }
            #pragma unroll
            for (int n = 0; n < 4; ++n) ngsj[n] = g2 * sq[ntj * TB + n * 16 + lr];
        }

        // epilogue: e = min(c2*idot - (gsi+gsj), 0); u = 2^e; 5 powers
        bool strad = ((tj >> 1) == ti);
        float lanesum = 0.f;
        #pragma unroll
        for (int m = 0; m < 2; ++m) {
            #pragma unroll
            for (int r = 0; r < 4; ++r) {
                float gi_s = gsi[m][r];
                #pragma unroll
                for (int n = 0; n < 4; ++n) {
                    float fd = (float)acc[m][n][r];
                    float e  = fminf(fmaf(c2, fd, -(gi_s + gsj[n])), 0.f);
                    float uu = EXP2F(e);
                    float u2 = uu * uu, u4 = u2 * u2, u8 = u4 * u4, u16 = u8 * u8;
                    float s5 = uu + u2 + u4 + u8 + u16;
                    if (strad) {
                        int gi = ti * TA + wid * 32 + m * 16 + lk * 4 + r;
                        int gj = tj * TB + n * 16 + lr;
                        float w = (gj > gi) ? 2.f : ((gj == gi) ? 1.f : 0.f);
                        lanesum = fmaf(w, s5, lanesum);
                    } else {
                        lanesum += s5;
                    }
                }
            }
        }
        float sgn = ((ti < NTA / 2) == (tj < NTB / 2)) ? 1.f : -1.f;
        running = fmaf(strad ? sgn : 2.f * sgn, lanesum, running);

        // rotate state
        if (p + 1 < pend) {
            #pragma unroll
            for (int m = 0; m < 2; ++m)
                #pragma unroll
                for (int r = 0; r < 4; ++r) gsi[m][r] = ngsi[m][r];
            #pragma unroll
            for (int n = 0; n < 4; ++n) gsj[n] = ngsj[n];
        }
        ti = nti; tj = ntj; cur ^= 1;
    }

    // one reduce + one atomic per wave
    #pragma unroll
    for (int off = 32; off; off >>= 1) running += __shfl_xor(running, off, 64);
    if (lane == 0)
        atomicAdd(&bins[((sw << 2) + wid) & (NBINS - 1)], (double)running);

    __syncthreads();
    if (t == 0) {
        __threadfence();
        unsigned old = atomicAdd(counter, 1u);
        if (old == NGRID - 1) {              // last block finalizes
            __threadfence();
            double tot = 0.0;
            for (int i = 0; i < NBINS; ++i)
                tot += ((volatile double*)bins)[i];
            out[0] = (float)(tot / ((double)BHALF * (double)BHALF));
        }
    }
}

extern "C" void kernel_launch(void* const* d_in, const int* in_sizes, int n_in,
                              void* d_out, int out_size, void* d_ws, size_t ws_size,
                              hipStream_t stream) {
    const float* src = (const float*)d_in[0];
    const float* tar = (const float*)d_in[1];
    float* out = (float*)d_out;

    char* ws = (char*)d_ws;
    double*   sumsq   = (double*)(ws + 0);
    unsigned* counter = (unsigned*)(ws + 8);
    double*   bins    = (double*)(ws + 16);
    float*    colsum  = (float*)(ws + 1024);
    float*    sq      = (float*)(ws + 4096);
    signed char* Ti   = (signed char*)(ws + 36864);

    hipMemsetAsync(ws, 0, 2048, stream);
    pre_kernel<<<256, 256, 0, stream>>>(src, tar, sq, colsum, sumsq, Ti);
    mmd_main<<<NGRID, 256, 0, stream>>>(Ti, sq, colsum, sumsq, bins, counter, out);
}